// Round 17
// baseline (203.862 us; speedup 1.0000x reference)
//
#include <hip/hip_runtime.h>

// GCN layer: out = ReLU(BN(GCNConv(x) + x@skip_W))
// R35 = R34 resubmit (R34 hit GPUAcquisitionTimeout, never ran).
// R34: R33 (196.1us, session best) + isolated split-xd8 A/B test.
//      k_agg's gather table is 6.4MB > 4MB per-XCD L2 -> random gather pays
//      L3 latency. Split into xd8a/xd8b (3.2MB each, dims 0-31 / 32-63) and
//      run k_agg TWICE (temporal separation -> each pass's table L2-resident
//      per XCD). Costs one extra launch + re-streaming csr (+7MB); numerics
//      bit-identical (per-dim sums independent).
//      Everything else = R33 verbatim.

typedef unsigned short ushort;
typedef __bf16 bf16x8 __attribute__((ext_vector_type(8)));
typedef float f32x4 __attribute__((ext_vector_type(4)));
typedef float f32x2 __attribute__((ext_vector_type(2)));
typedef ushort u16x8 __attribute__((ext_vector_type(8)));

constexpr int N_NODES = 100000;
constexpr int N_PAD   = 100096;                  // 782*128
constexpr int E_EDGES = 1600000;

constexpr int BUCK_SHIFT = 7;                    // 128 nodes per bucket
constexpr int NBUCK   = (N_NODES + 127) / 128;   // 782
constexpr int CHUNK   = 4096;
constexpr int NCHUNK  = (E_EDGES + CHUNK - 1) / CHUNK;  // 391
constexpr int CAP     = 4096;                    // bucket region capacity
constexpr int SORT_CAP = 4096;
constexpr int GG      = 256;                     // gemm grid

// ws layout (4-byte element offsets) — audited:
constexpr size_t OFF_SCALE  = 0;                 // 256 floats
constexpr size_t OFF_DINV   = 256;               // 100000 -> ends 100256
constexpr size_t OFF_ROWPTR = 100352;            // 100000 ints -> ends 200352
constexpr size_t OFF_DEG    = 200448;            // 100000 ints -> ends 300448
constexpr size_t OFF_GCNT   = 300544;            // 782 ints -> ends 301326
constexpr size_t OFF_BINNED = 301568;            // 782*4096 uints -> ends 3504640
constexpr size_t OFF_PART   = OFF_BINNED;        // partial aliases binned (dead after agg)
constexpr size_t OFF_A      = 3504640;           // N_PAD*128 bf16 -> +6406144 -> ends 9910784
constexpr size_t OFF_PRE    = 9910784;           // +6406144 -> ends 16316928
constexpr size_t OFF_XD8A   = OFF_PRE;           // N_PAD*8 uints = 800768 (aliases pre, dead by gemm)
constexpr size_t OFF_XD8B   = OFF_PRE + 800768;  // 800768 more (still inside pre's 6406144)
constexpr size_t OFF_BT     = 16316928;          // +8192 -> ends 16325120 (~65.3MB)

static __device__ __forceinline__ ushort f2bf(float f) {
    union { float f; unsigned u; } v; v.f = f;
    unsigned r = v.u + 0x7FFFu + ((v.u >> 16) & 1u);  // RNE
    return (ushort)(r >> 16);
}
static __device__ __forceinline__ float bf2f(ushort u) {
    union { unsigned u; float f; } v; v.u = (unsigned)u << 16;
    return v.f;
}
static __device__ __forceinline__ unsigned pack_fp8x4(float a, float b, float c, float d) {
    int r = 0;
    r = __builtin_amdgcn_cvt_pk_fp8_f32(a, b, r, false);
    r = __builtin_amdgcn_cvt_pk_fp8_f32(c, d, r, true);
    return (unsigned)r;
}

// ---- init: zero gcnt (block 0) + Bt prep (blocks 1..64) ----
__global__ __launch_bounds__(256) void k_init(const float* __restrict__ W,
                                              const float* __restrict__ skipW,
                                              ushort* __restrict__ Bt,
                                              int* __restrict__ gcnt) {
    int t = threadIdx.x;
    if (blockIdx.x == 0) {
        for (int b = t; b < NBUCK; b += 256) gcnt[b] = 0;
        return;
    }
    int idx = (blockIdx.x - 1) * 256 + t;        // 0..16383
    int k = idx >> 7, n = idx & 127;
    float v = (k < 64) ? W[k * 128 + n] : skipW[(k - 64) * 128 + n];
    Bt[n * 128 + k] = f2bf(v);
}

// ---- scatter: per-chunk LDS hist -> global range reservation -> place ----
__global__ __launch_bounds__(512) void k_scatter(const int* __restrict__ row,
                                                 const int* __restrict__ col,
                                                 int* __restrict__ gcnt,
                                                 unsigned int* __restrict__ binned) {
    __shared__ int h[NBUCK];
    __shared__ int bb[NBUCK];
    int c = blockIdx.x, t = threadIdx.x;
    for (int b = t; b < NBUCK; b += 512) h[b] = 0;
    __syncthreads();
    const int4* col4 = (const int4*)col;
    const int4* row4 = (const int4*)row;
    int g0 = c * (CHUNK / 4);
    // pass A: local histogram
#pragma unroll
    for (int i = 0; i < CHUNK / 2048; ++i) {
        int g4 = g0 + i * 512 + t;
        if (g4 * 4 + 3 < E_EDGES) {
            int4 cc = col4[g4];
            atomicAdd(&h[cc.x >> BUCK_SHIFT], 1);
            atomicAdd(&h[cc.y >> BUCK_SHIFT], 1);
            atomicAdd(&h[cc.z >> BUCK_SHIFT], 1);
            atomicAdd(&h[cc.w >> BUCK_SHIFT], 1);
        } else {
#pragma unroll
            for (int j = 0; j < 4; ++j) {
                int e = g4 * 4 + j;
                if (e < E_EDGES) atomicAdd(&h[col[e] >> BUCK_SHIFT], 1);
            }
        }
    }
    __syncthreads();
    // pass B: reserve disjoint ranges in each bucket region
    for (int b = t; b < NBUCK; b += 512) {
        int cb = h[b];
        bb[b] = cb ? atomicAdd(&gcnt[b], cb) : 0;
        h[b] = 0;                                 // reuse as cursor
    }
    __syncthreads();
    // pass C: place edges (chunk data L2-hot from pass A)
#pragma unroll
    for (int i = 0; i < CHUNK / 2048; ++i) {
        int g4 = g0 + i * 512 + t;
        if (g4 * 4 + 3 < E_EDGES) {
            int4 cc = col4[g4];
            int4 rr = row4[g4];
            int b, p;
            b = cc.x >> BUCK_SHIFT; p = bb[b] + atomicAdd(&h[b], 1);
            if (p < CAP) binned[(size_t)b * CAP + p] = ((unsigned)(cc.x & 127) << 17) | (unsigned)rr.x;
            b = cc.y >> BUCK_SHIFT; p = bb[b] + atomicAdd(&h[b], 1);
            if (p < CAP) binned[(size_t)b * CAP + p] = ((unsigned)(cc.y & 127) << 17) | (unsigned)rr.y;
            b = cc.z >> BUCK_SHIFT; p = bb[b] + atomicAdd(&h[b], 1);
            if (p < CAP) binned[(size_t)b * CAP + p] = ((unsigned)(cc.z & 127) << 17) | (unsigned)rr.z;
            b = cc.w >> BUCK_SHIFT; p = bb[b] + atomicAdd(&h[b], 1);
            if (p < CAP) binned[(size_t)b * CAP + p] = ((unsigned)(cc.w & 127) << 17) | (unsigned)rr.w;
        } else {
#pragma unroll
            for (int j = 0; j < 4; ++j) {
                int e = g4 * 4 + j;
                if (e < E_EDGES) {
                    int d = col[e], s = row[e];
                    int b = d >> BUCK_SHIFT;
                    int p = bb[b] + atomicAdd(&h[b], 1);
                    if (p < CAP) binned[(size_t)b * CAP + p] = ((unsigned)(d & 127) << 17) | (unsigned)s;
                }
            }
        }
    }
}

// ---- per-bucket counting sort -> csr, rowptr, deg, dinv; fused fp8 cast (split) + A x-half ----
__global__ __launch_bounds__(256) void k_sortbucket(unsigned int* __restrict__ binned,
                                                    const int* __restrict__ gcnt,
                                                    int* __restrict__ rowptr,
                                                    int* __restrict__ deg,
                                                    float* __restrict__ dinv,
                                                    const float* __restrict__ x,
                                                    unsigned* __restrict__ xd8a,
                                                    unsigned* __restrict__ xd8b,
                                                    ushort* __restrict__ A) {
    __shared__ unsigned int ebuf[SORT_CAP];
    __shared__ int sbuf[SORT_CAP];
    __shared__ int lcnt[128];
    __shared__ int lptr[128];
    __shared__ float ldinv[128];
    __shared__ int wsum[2];
    int b = blockIdx.x, t = threadIdx.x;
    int i0 = b * CAP;
    int cnt = min(gcnt[b], CAP);
    int n0 = b << BUCK_SHIFT;
    int nn = min(128, N_NODES - n0);

    for (int k = t; k < cnt; k += 256) ebuf[k] = binned[i0 + k];
    if (t < 128) lcnt[t] = 0;
    __syncthreads();
    for (int k = t; k < cnt; k += 256) atomicAdd(&lcnt[ebuf[k] >> 17], 1);
    __syncthreads();

    // 128-wide exclusive scan via 2-wave shfl
    int myc = 0, val = 0;
    if (t < 128) {
        myc = lcnt[t];
        val = myc;
#pragma unroll
        for (int d = 1; d < 64; d <<= 1) {
            int o = __shfl_up(val, d);
            if ((t & 63) >= d) val += o;
        }
        if ((t & 63) == 63) wsum[t >> 6] = val;
    }
    __syncthreads();
    if (t < 128) {
        if (t >= 64) val += wsum[0];
        int excl = val - myc;
        lptr[t] = excl;
        float dv = rsqrtf((float)myc + 1.0f);  // +1 self loop
        ldinv[t] = dv;
        if (t < nn) {
            rowptr[n0 + t] = i0 + excl;
            deg[n0 + t] = myc;
            dinv[n0 + t] = dv;
        }
    }
    __syncthreads();
    for (int k = t; k < cnt; k += 256) {
        unsigned int e = ebuf[k];
        int j = (int)(e >> 17);
        int p = atomicAdd(&lptr[j], 1);
        sbuf[p] = (int)(e & 0x1FFFF);
    }
    __syncthreads();
    for (int k = t; k < cnt; k += 256) binned[i0 + k] = (unsigned int)sbuf[k];

    // fused cast: xd8a/b = fp8(x*dinv) split by dim half; A cols 64..127 = bf16(x)
#pragma unroll
    for (int it = 0; it < 8; ++it) {
        int idx = it * 256 + t;          // 0..2047
        int nl = idx >> 4, q = idx & 15;
        int c = n0 + nl;
        unsigned w8 = 0;
        ushort4 xb = {0, 0, 0, 0};
        if (nl < nn) {
            float4 v = ((const float4*)x)[(size_t)c * 16 + q];
            float d = ldinv[nl];
            w8 = pack_fp8x4(v.x * d, v.y * d, v.z * d, v.w * d);
            xb.x = f2bf(v.x); xb.y = f2bf(v.y); xb.z = f2bf(v.z); xb.w = f2bf(v.w);
        }
        if (q < 8) xd8a[(size_t)c * 8 + q] = w8;
        else       xd8b[(size_t)c * 8 + (q - 8)] = w8;
        ((ushort4*)A)[(size_t)c * 32 + 16 + q] = xb;   // cols 64..127
    }
}

// ---- aggregation (one dim-half): 8 lanes per node; L2-resident 3.2MB table ----
__global__ __launch_bounds__(256) void k_agg_half(const unsigned* __restrict__ tab,
                                                  const float* __restrict__ dinv,
                                                  const int* __restrict__ rowptr,
                                                  const int* __restrict__ deg,
                                                  const unsigned int* __restrict__ csr,
                                                  ushort* __restrict__ A,
                                                  int woff) {
    int t = blockIdx.x * blockDim.x + threadIdx.x;
    if (t >= N_PAD * 8) return;
    int c = t >> 3;
    int q = t & 7;
    if (c >= N_NODES) {
        ushort4 z = {0, 0, 0, 0};
        ((ushort4*)A)[(size_t)c * 32 + woff + q] = z;
        return;
    }
    float dc = dinv[c];
    float4 acc;
    {
        unsigned w = tab[(size_t)c * 8 + q];
        f32x2 lo = __builtin_amdgcn_cvt_pk_f32_fp8((int)w, false);
        f32x2 hi = __builtin_amdgcn_cvt_pk_f32_fp8((int)w, true);
        acc.x = lo.x; acc.y = lo.y; acc.z = hi.x; acc.w = hi.y;
    }
    int i0 = rowptr[c], i1 = i0 + deg[c];
    int i = i0;
    for (; i + 8 <= i1; i += 8) {
        int s[8];
#pragma unroll
        for (int k = 0; k < 8; ++k) s[k] = (int)csr[i + k];
        unsigned w[8];
#pragma unroll
        for (int k = 0; k < 8; ++k) w[k] = tab[(size_t)s[k] * 8 + q];
#pragma unroll
        for (int k = 0; k < 8; ++k) {
            f32x2 lo = __builtin_amdgcn_cvt_pk_f32_fp8((int)w[k], false);
            f32x2 hi = __builtin_amdgcn_cvt_pk_f32_fp8((int)w[k], true);
            acc.x += lo.x; acc.y += lo.y; acc.z += hi.x; acc.w += hi.y;
        }
    }
    for (; i < i1; ++i) {
        unsigned w = tab[(size_t)csr[i] * 8 + q];
        f32x2 lo = __builtin_amdgcn_cvt_pk_f32_fp8((int)w, false);
        f32x2 hi = __builtin_amdgcn_cvt_pk_f32_fp8((int)w, true);
        acc.x += lo.x; acc.y += lo.y; acc.z += hi.x; acc.w += hi.y;
    }
    ushort4 o;
    o.x = f2bf(acc.x * dc); o.y = f2bf(acc.y * dc);
    o.z = f2bf(acc.z * dc); o.w = f2bf(acc.w * dc);
    ((ushort4*)A)[(size_t)c * 32 + woff + q] = o;      // cols (woff*4)..(woff*4+31)
}

// ---- MFMA GEMM: pre = A @ Bt^T (bf16 out, bias cancels in BN); BN partials ----
__global__ __launch_bounds__(512, 2) void k_gemm(const ushort* __restrict__ A,
                                                 const ushort* __restrict__ Bt,
                                                 ushort* __restrict__ pre,
                                                 float* __restrict__ partial) {
    __shared__ float sred[128];
    __shared__ float qred[128];
    int tid = threadIdx.x;
    int wave = tid >> 6, lane = tid & 63;
    int wm = wave >> 2, wn = wave & 3;
    int l15 = lane & 15, quad = lane >> 4;
    int col0 = wn * 32;

    if (tid < 128) { sred[tid] = 0.f; qred[tid] = 0.f; }
    __syncthreads();

    bf16x8 bf_[4][2];
#pragma unroll
    for (int kc = 0; kc < 4; ++kc)
#pragma unroll
        for (int jc = 0; jc < 2; ++jc)
            bf_[kc][jc] = *(const bf16x8*)&Bt[(size_t)(col0 + jc * 16 + l15) * 128 + kc * 32 + quad * 8];

    float lsum[8] = {0.f, 0.f, 0.f, 0.f, 0.f, 0.f, 0.f, 0.f};
    float lsq[8]  = {0.f, 0.f, 0.f, 0.f, 0.f, 0.f, 0.f, 0.f};

    for (int ci = blockIdx.x; ci < NBUCK; ci += GG) {
        int row0 = ci * 128 + wm * 64;
        bf16x8 af[4][4];
#pragma unroll
        for (int kc = 0; kc < 4; ++kc)
#pragma unroll
            for (int ir = 0; ir < 4; ++ir)
                af[kc][ir] = *(const bf16x8*)&A[(size_t)(row0 + ir * 16 + l15) * 128 + kc * 32 + quad * 8];

        f32x4 acc[4][2];
#pragma unroll
        for (int ir = 0; ir < 4; ++ir)
#pragma unroll
            for (int jc = 0; jc < 2; ++jc) acc[ir][jc] = (f32x4){0.f, 0.f, 0.f, 0.f};

#pragma unroll
        for (int kc = 0; kc < 4; ++kc)
#pragma unroll
            for (int ir = 0; ir < 4; ++ir)
#pragma unroll
                for (int jc = 0; jc < 2; ++jc)
                    acc[ir][jc] = __builtin_amdgcn_mfma_f32_16x16x32_bf16(
                        bf_[kc][jc], af[kc][ir], acc[ir][jc], 0, 0, 0);

#pragma unroll
        for (int ir = 0; ir < 4; ++ir) {
            int row = row0 + ir * 16 + l15;
            bool live = row < N_NODES;
#pragma unroll
            for (int jc = 0; jc < 2; ++jc) {
                ushort4 o;
                o.x = f2bf(acc[ir][jc][0]); o.y = f2bf(acc[ir][jc][1]);
                o.z = f2bf(acc[ir][jc][2]); o.w = f2bf(acc[ir][jc][3]);
                *(ushort4*)&pre[(size_t)row * 128 + col0 + jc * 16 + quad * 4] = o;
                if (live) {
#pragma unroll
                    for (int r = 0; r < 4; ++r) {
                        float v = acc[ir][jc][r];
                        lsum[jc * 4 + r] += v;
                        lsq[jc * 4 + r]  += v * v;
                    }
                }
            }
        }
    }

#pragma unroll
    for (int m = 1; m < 16; m <<= 1) {
#pragma unroll
        for (int i = 0; i < 8; ++i) {
            lsum[i] += __shfl_xor(lsum[i], m);
            lsq[i]  += __shfl_xor(lsq[i], m);
        }
    }
    if (l15 == 0) {
#pragma unroll
        for (int jc = 0; jc < 2; ++jc)
#pragma unroll
            for (int r = 0; r < 4; ++r) {
                int c = col0 + jc * 16 + quad * 4 + r;
                atomicAdd(&sred[c], lsum[jc * 4 + r]);
                atomicAdd(&qred[c], lsq[jc * 4 + r]);
            }
    }
    __syncthreads();
    if (tid < 128) {
        partial[(size_t)blockIdx.x * 256 + tid]       = sred[tid];
        partial[(size_t)blockIdx.x * 256 + 128 + tid] = qred[tid];
    }
}

// ---- reduce GG partials -> scale/shift (one block per output column) ----
__global__ __launch_bounds__(256) void k_reduce(const float* __restrict__ partial,
                                                const float* __restrict__ gamma,
                                                const float* __restrict__ beta,
                                                float* __restrict__ scaleshift) {
    __shared__ float ls[256], lq[256];
    int j = blockIdx.x;   // 0..127
    int t = threadIdx.x;
    float s = 0.f, q = 0.f;
    for (int p = t; p < GG; p += 256) {
        s += partial[(size_t)p * 256 + j];
        q += partial[(size_t)p * 256 + 128 + j];
    }
    ls[t] = s; lq[t] = q;
    __syncthreads();
#pragma unroll
    for (int off = 128; off > 0; off >>= 1) {
        if (t < off) { ls[t] += ls[t + off]; lq[t] += lq[t + off]; }
        __syncthreads();
    }
    if (t == 0) {
        float mean = ls[0] * (1.0f / N_NODES);
        float var  = lq[0] * (1.0f / N_NODES) - mean * mean;
        float sc   = gamma[j] * rsqrtf(var + 1e-5f);
        scaleshift[j]       = sc;
        scaleshift[128 + j] = beta[j] - mean * sc;
    }
}

// read bf16 pre (8/thread), write fp32 out (32B/thread)
__global__ __launch_bounds__(256) void k_apply(const ushort* __restrict__ pre,
                                               float* __restrict__ out,
                                               const float* __restrict__ ss) {
    int t = blockIdx.x * blockDim.x + threadIdx.x;
    if (t >= N_NODES * 16) return;
    int j8 = t & 15;
    u16x8 p = ((const u16x8*)pre)[t];
    float4 sc0 = ((const float4*)ss)[j8 * 2];
    float4 sc1 = ((const float4*)ss)[j8 * 2 + 1];
    float4 sh0 = ((const float4*)(ss + 128))[j8 * 2];
    float4 sh1 = ((const float4*)(ss + 128))[j8 * 2 + 1];
    float4 v0, v1;
    v0.x = fmaxf(fmaf(bf2f(p[0]), sc0.x, sh0.x), 0.f);
    v0.y = fmaxf(fmaf(bf2f(p[1]), sc0.y, sh0.y), 0.f);
    v0.z = fmaxf(fmaf(bf2f(p[2]), sc0.z, sh0.z), 0.f);
    v0.w = fmaxf(fmaf(bf2f(p[3]), sc0.w, sh0.w), 0.f);
    v1.x = fmaxf(fmaf(bf2f(p[4]), sc1.x, sh1.x), 0.f);
    v1.y = fmaxf(fmaf(bf2f(p[5]), sc1.y, sh1.y), 0.f);
    v1.z = fmaxf(fmaf(bf2f(p[6]), sc1.z, sh1.z), 0.f);
    v1.w = fmaxf(fmaf(bf2f(p[7]), sc1.w, sh1.w), 0.f);
    ((float4*)out)[t * 2]     = v0;
    ((float4*)out)[t * 2 + 1] = v1;
}

extern "C" void kernel_launch(void* const* d_in, const int* in_sizes, int n_in,
                              void* d_out, int out_size, void* d_ws, size_t ws_size,
                              hipStream_t stream) {
    const float* x      = (const float*)d_in[0];
    const int*   eidx   = (const int*)d_in[1];
    const float* W      = (const float*)d_in[2];
    const float* skipW  = (const float*)d_in[4];
    const float* gamma  = (const float*)d_in[5];
    const float* beta   = (const float*)d_in[6];
    float* out = (float*)d_out;
    float* ws  = (float*)d_ws;

    const int* row = eidx;
    const int* col = eidx + E_EDGES;

    float* scaleshift = ws + OFF_SCALE;
    float* dinv       = ws + OFF_DINV;
    int*   rowptr     = (int*)(ws + OFF_ROWPTR);
    int*   deg        = (int*)(ws + OFF_DEG);
    int*   gcnt       = (int*)(ws + OFF_GCNT);
    unsigned int* binned = (unsigned int*)(ws + OFF_BINNED);
    float* partial    = ws + OFF_PART;             // aliases binned (dead after agg)
    ushort* A         = (ushort*)(ws + OFF_A);
    unsigned* xd8a    = (unsigned*)(ws + OFF_XD8A); // aliases pre (dead by gemm)
    unsigned* xd8b    = (unsigned*)(ws + OFF_XD8B);
    ushort* pre       = (ushort*)(ws + OFF_PRE);
    ushort* Bt        = (ushort*)(ws + OFF_BT);

    k_init<<<65, 256, 0, stream>>>(W, skipW, Bt, gcnt);
    k_scatter<<<NCHUNK, 512, 0, stream>>>(row, col, gcnt, binned);
    k_sortbucket<<<NBUCK, 256, 0, stream>>>(binned, gcnt, rowptr, deg, dinv, x, xd8a, xd8b, A);
    k_agg_half<<<(N_PAD * 8 + 255) / 256, 256, 0, stream>>>(xd8a, dinv, rowptr, deg, binned, A, 0);
    k_agg_half<<<(N_PAD * 8 + 255) / 256, 256, 0, stream>>>(xd8b, dinv, rowptr, deg, binned, A, 8);
    k_gemm<<<GG, 512, 0, stream>>>(A, Bt, pre, partial);
    k_reduce<<<128, 256, 0, stream>>>(partial, gamma, beta, scaleshift);
    k_apply<<<(N_NODES * 16 + 255) / 256, 256, 0, stream>>>(pre, out, scaleshift);
}

// Round 18
// 193.789 us; speedup vs baseline: 1.0520x; 1.0520x over previous
//
#include <hip/hip_runtime.h>

// GCN layer: out = ReLU(BN(GCNConv(x) + x@skip_W))
// R36 = R33 verbatim (196.1us, session best). R35's split-xd8 A/B test came
//      back NEGATIVE (203.9us, +7.7): TLP already hides the gather's L3
//      latency; the split's extra launch + double-streamed csr/rowptr/deg
//      cost more than L2 residency bought. That was the last unmeasured
//      mechanism — reverting to lock in the best configuration.
// R33: R25 pipeline + k_scatter at CHUNK=4096 / 512 threads.

typedef unsigned short ushort;
typedef __bf16 bf16x8 __attribute__((ext_vector_type(8)));
typedef float f32x4 __attribute__((ext_vector_type(4)));
typedef float f32x2 __attribute__((ext_vector_type(2)));
typedef ushort u16x8 __attribute__((ext_vector_type(8)));

constexpr int N_NODES = 100000;
constexpr int N_PAD   = 100096;                  // 782*128
constexpr int E_EDGES = 1600000;

constexpr int BUCK_SHIFT = 7;                    // 128 nodes per bucket
constexpr int NBUCK   = (N_NODES + 127) / 128;   // 782
constexpr int CHUNK   = 4096;
constexpr int NCHUNK  = (E_EDGES + CHUNK - 1) / CHUNK;  // 391
constexpr int CAP     = 4096;                    // bucket region capacity
constexpr int SORT_CAP = 4096;
constexpr int GG      = 256;                     // gemm grid

// ws layout (4-byte element offsets) — audited (R25's):
constexpr size_t OFF_SCALE  = 0;                 // 256 floats
constexpr size_t OFF_DINV   = 256;               // 100000 -> ends 100256
constexpr size_t OFF_ROWPTR = 100352;            // 100000 ints -> ends 200352
constexpr size_t OFF_DEG    = 200448;            // 100000 ints -> ends 300448
constexpr size_t OFF_GCNT   = 300544;            // 782 ints -> ends 301326
constexpr size_t OFF_BINNED = 301568;            // 782*4096 uints -> ends 3504640
constexpr size_t OFF_PART   = OFF_BINNED;        // partial aliases binned (dead after agg)
constexpr size_t OFF_A      = 3504640;           // N_PAD*128 bf16 -> +6406144 -> ends 9910784
constexpr size_t OFF_PRE    = 9910784;           // +6406144 -> ends 16316928
constexpr size_t OFF_XD8    = OFF_PRE;           // xd8 (N_PAD*16 uint) aliases pre (dead by gemm)
constexpr size_t OFF_BT     = 16316928;          // +8192 -> ends 16325120 (~65.3MB)

static __device__ __forceinline__ ushort f2bf(float f) {
    union { float f; unsigned u; } v; v.f = f;
    unsigned r = v.u + 0x7FFFu + ((v.u >> 16) & 1u);  // RNE
    return (ushort)(r >> 16);
}
static __device__ __forceinline__ float bf2f(ushort u) {
    union { unsigned u; float f; } v; v.u = (unsigned)u << 16;
    return v.f;
}
static __device__ __forceinline__ unsigned pack_fp8x4(float a, float b, float c, float d) {
    int r = 0;
    r = __builtin_amdgcn_cvt_pk_fp8_f32(a, b, r, false);
    r = __builtin_amdgcn_cvt_pk_fp8_f32(c, d, r, true);
    return (unsigned)r;
}

// ---- init: zero gcnt (block 0) + Bt prep (blocks 1..64) ----
__global__ __launch_bounds__(256) void k_init(const float* __restrict__ W,
                                              const float* __restrict__ skipW,
                                              ushort* __restrict__ Bt,
                                              int* __restrict__ gcnt) {
    int t = threadIdx.x;
    if (blockIdx.x == 0) {
        for (int b = t; b < NBUCK; b += 256) gcnt[b] = 0;
        return;
    }
    int idx = (blockIdx.x - 1) * 256 + t;        // 0..16383
    int k = idx >> 7, n = idx & 127;
    float v = (k < 64) ? W[k * 128 + n] : skipW[(k - 64) * 128 + n];
    Bt[n * 128 + k] = f2bf(v);
}

// ---- scatter: per-chunk LDS hist -> global range reservation -> place ----
__global__ __launch_bounds__(512) void k_scatter(const int* __restrict__ row,
                                                 const int* __restrict__ col,
                                                 int* __restrict__ gcnt,
                                                 unsigned int* __restrict__ binned) {
    __shared__ int h[NBUCK];
    __shared__ int bb[NBUCK];
    int c = blockIdx.x, t = threadIdx.x;
    for (int b = t; b < NBUCK; b += 512) h[b] = 0;
    __syncthreads();
    const int4* col4 = (const int4*)col;
    const int4* row4 = (const int4*)row;
    int g0 = c * (CHUNK / 4);
    // pass A: local histogram
#pragma unroll
    for (int i = 0; i < CHUNK / 2048; ++i) {
        int g4 = g0 + i * 512 + t;
        if (g4 * 4 + 3 < E_EDGES) {
            int4 cc = col4[g4];
            atomicAdd(&h[cc.x >> BUCK_SHIFT], 1);
            atomicAdd(&h[cc.y >> BUCK_SHIFT], 1);
            atomicAdd(&h[cc.z >> BUCK_SHIFT], 1);
            atomicAdd(&h[cc.w >> BUCK_SHIFT], 1);
        } else {
#pragma unroll
            for (int j = 0; j < 4; ++j) {
                int e = g4 * 4 + j;
                if (e < E_EDGES) atomicAdd(&h[col[e] >> BUCK_SHIFT], 1);
            }
        }
    }
    __syncthreads();
    // pass B: reserve disjoint ranges in each bucket region
    for (int b = t; b < NBUCK; b += 512) {
        int cb = h[b];
        bb[b] = cb ? atomicAdd(&gcnt[b], cb) : 0;
        h[b] = 0;                                 // reuse as cursor
    }
    __syncthreads();
    // pass C: place edges (chunk data L2-hot from pass A)
#pragma unroll
    for (int i = 0; i < CHUNK / 2048; ++i) {
        int g4 = g0 + i * 512 + t;
        if (g4 * 4 + 3 < E_EDGES) {
            int4 cc = col4[g4];
            int4 rr = row4[g4];
            int b, p;
            b = cc.x >> BUCK_SHIFT; p = bb[b] + atomicAdd(&h[b], 1);
            if (p < CAP) binned[(size_t)b * CAP + p] = ((unsigned)(cc.x & 127) << 17) | (unsigned)rr.x;
            b = cc.y >> BUCK_SHIFT; p = bb[b] + atomicAdd(&h[b], 1);
            if (p < CAP) binned[(size_t)b * CAP + p] = ((unsigned)(cc.y & 127) << 17) | (unsigned)rr.y;
            b = cc.z >> BUCK_SHIFT; p = bb[b] + atomicAdd(&h[b], 1);
            if (p < CAP) binned[(size_t)b * CAP + p] = ((unsigned)(cc.z & 127) << 17) | (unsigned)rr.z;
            b = cc.w >> BUCK_SHIFT; p = bb[b] + atomicAdd(&h[b], 1);
            if (p < CAP) binned[(size_t)b * CAP + p] = ((unsigned)(cc.w & 127) << 17) | (unsigned)rr.w;
        } else {
#pragma unroll
            for (int j = 0; j < 4; ++j) {
                int e = g4 * 4 + j;
                if (e < E_EDGES) {
                    int d = col[e], s = row[e];
                    int b = d >> BUCK_SHIFT;
                    int p = bb[b] + atomicAdd(&h[b], 1);
                    if (p < CAP) binned[(size_t)b * CAP + p] = ((unsigned)(d & 127) << 17) | (unsigned)s;
                }
            }
        }
    }
}

// ---- per-bucket counting sort -> csr, rowptr, deg, dinv; fused fp8 cast + A x-half ----
__global__ __launch_bounds__(256) void k_sortbucket(unsigned int* __restrict__ binned,
                                                    const int* __restrict__ gcnt,
                                                    int* __restrict__ rowptr,
                                                    int* __restrict__ deg,
                                                    float* __restrict__ dinv,
                                                    const float* __restrict__ x,
                                                    unsigned* __restrict__ xd8,
                                                    ushort* __restrict__ A) {
    __shared__ unsigned int ebuf[SORT_CAP];
    __shared__ int sbuf[SORT_CAP];
    __shared__ int lcnt[128];
    __shared__ int lptr[128];
    __shared__ float ldinv[128];
    __shared__ int wsum[2];
    int b = blockIdx.x, t = threadIdx.x;
    int i0 = b * CAP;
    int cnt = min(gcnt[b], CAP);
    int n0 = b << BUCK_SHIFT;
    int nn = min(128, N_NODES - n0);

    for (int k = t; k < cnt; k += 256) ebuf[k] = binned[i0 + k];
    if (t < 128) lcnt[t] = 0;
    __syncthreads();
    for (int k = t; k < cnt; k += 256) atomicAdd(&lcnt[ebuf[k] >> 17], 1);
    __syncthreads();

    // 128-wide exclusive scan via 2-wave shfl
    int myc = 0, val = 0;
    if (t < 128) {
        myc = lcnt[t];
        val = myc;
#pragma unroll
        for (int d = 1; d < 64; d <<= 1) {
            int o = __shfl_up(val, d);
            if ((t & 63) >= d) val += o;
        }
        if ((t & 63) == 63) wsum[t >> 6] = val;
    }
    __syncthreads();
    if (t < 128) {
        if (t >= 64) val += wsum[0];
        int excl = val - myc;
        lptr[t] = excl;
        float dv = rsqrtf((float)myc + 1.0f);  // +1 self loop
        ldinv[t] = dv;
        if (t < nn) {
            rowptr[n0 + t] = i0 + excl;
            deg[n0 + t] = myc;
            dinv[n0 + t] = dv;
        }
    }
    __syncthreads();
    for (int k = t; k < cnt; k += 256) {
        unsigned int e = ebuf[k];
        int j = (int)(e >> 17);
        int p = atomicAdd(&lptr[j], 1);
        sbuf[p] = (int)(e & 0x1FFFF);
    }
    __syncthreads();
    for (int k = t; k < cnt; k += 256) binned[i0 + k] = (unsigned int)sbuf[k];

    // fused cast: xd8 = fp8(x*dinv); A cols 64..127 = bf16(raw x); zero pad rows
#pragma unroll
    for (int it = 0; it < 8; ++it) {
        int idx = it * 256 + t;          // 0..2047
        int nl = idx >> 4, q = idx & 15;
        int c = n0 + nl;
        unsigned w8 = 0;
        ushort4 xb = {0, 0, 0, 0};
        if (nl < nn) {
            float4 v = ((const float4*)x)[(size_t)c * 16 + q];
            float d = ldinv[nl];
            w8 = pack_fp8x4(v.x * d, v.y * d, v.z * d, v.w * d);
            xb.x = f2bf(v.x); xb.y = f2bf(v.y); xb.z = f2bf(v.z); xb.w = f2bf(v.w);
        }
        xd8[(size_t)c * 16 + q] = w8;
        ((ushort4*)A)[(size_t)c * 32 + 16 + q] = xb;   // cols 64..127
    }
}

// ---- aggregation: 16 lanes per node; fp8 gather; writes A cols 0..63 ----
__global__ __launch_bounds__(256) void k_agg(const unsigned* __restrict__ xd8,
                                             const float* __restrict__ dinv,
                                             const int* __restrict__ rowptr,
                                             const int* __restrict__ deg,
                                             const unsigned int* __restrict__ csr,
                                             ushort* __restrict__ A) {
    int t = blockIdx.x * blockDim.x + threadIdx.x;
    if (t >= N_PAD * 16) return;
    int c = t >> 4;
    int q = t & 15;
    if (c >= N_NODES) {
        ushort4 z = {0, 0, 0, 0};
        ((ushort4*)A)[(size_t)c * 32 + q] = z;
        return;
    }
    float dc = dinv[c];
    float4 acc;
    {
        unsigned w = xd8[t];
        f32x2 lo = __builtin_amdgcn_cvt_pk_f32_fp8((int)w, false);
        f32x2 hi = __builtin_amdgcn_cvt_pk_f32_fp8((int)w, true);
        acc.x = lo.x; acc.y = lo.y; acc.z = hi.x; acc.w = hi.y;
    }
    int i0 = rowptr[c], i1 = i0 + deg[c];
    int i = i0;
    for (; i + 8 <= i1; i += 8) {
        int s[8];
#pragma unroll
        for (int k = 0; k < 8; ++k) s[k] = (int)csr[i + k];
        unsigned w[8];
#pragma unroll
        for (int k = 0; k < 8; ++k) w[k] = xd8[s[k] * 16 + q];
#pragma unroll
        for (int k = 0; k < 8; ++k) {
            f32x2 lo = __builtin_amdgcn_cvt_pk_f32_fp8((int)w[k], false);
            f32x2 hi = __builtin_amdgcn_cvt_pk_f32_fp8((int)w[k], true);
            acc.x += lo.x; acc.y += lo.y; acc.z += hi.x; acc.w += hi.y;
        }
    }
    for (; i < i1; ++i) {
        unsigned w = xd8[(int)csr[i] * 16 + q];
        f32x2 lo = __builtin_amdgcn_cvt_pk_f32_fp8((int)w, false);
        f32x2 hi = __builtin_amdgcn_cvt_pk_f32_fp8((int)w, true);
        acc.x += lo.x; acc.y += lo.y; acc.z += hi.x; acc.w += hi.y;
    }
    ushort4 o;
    o.x = f2bf(acc.x * dc); o.y = f2bf(acc.y * dc);
    o.z = f2bf(acc.z * dc); o.w = f2bf(acc.w * dc);
    ((ushort4*)A)[(size_t)c * 32 + q] = o;             // cols 0..63
}

// ---- MFMA GEMM: pre = A @ Bt^T (bf16 out, bias cancels in BN); BN partials ----
__global__ __launch_bounds__(512, 2) void k_gemm(const ushort* __restrict__ A,
                                                 const ushort* __restrict__ Bt,
                                                 ushort* __restrict__ pre,
                                                 float* __restrict__ partial) {
    __shared__ float sred[128];
    __shared__ float qred[128];
    int tid = threadIdx.x;
    int wave = tid >> 6, lane = tid & 63;
    int wm = wave >> 2, wn = wave & 3;
    int l15 = lane & 15, quad = lane >> 4;
    int col0 = wn * 32;

    if (tid < 128) { sred[tid] = 0.f; qred[tid] = 0.f; }
    __syncthreads();

    bf16x8 bf_[4][2];
#pragma unroll
    for (int kc = 0; kc < 4; ++kc)
#pragma unroll
        for (int jc = 0; jc < 2; ++jc)
            bf_[kc][jc] = *(const bf16x8*)&Bt[(size_t)(col0 + jc * 16 + l15) * 128 + kc * 32 + quad * 8];

    float lsum[8] = {0.f, 0.f, 0.f, 0.f, 0.f, 0.f, 0.f, 0.f};
    float lsq[8]  = {0.f, 0.f, 0.f, 0.f, 0.f, 0.f, 0.f, 0.f};

    for (int ci = blockIdx.x; ci < NBUCK; ci += GG) {
        int row0 = ci * 128 + wm * 64;
        bf16x8 af[4][4];
#pragma unroll
        for (int kc = 0; kc < 4; ++kc)
#pragma unroll
            for (int ir = 0; ir < 4; ++ir)
                af[kc][ir] = *(const bf16x8*)&A[(size_t)(row0 + ir * 16 + l15) * 128 + kc * 32 + quad * 8];

        f32x4 acc[4][2];
#pragma unroll
        for (int ir = 0; ir < 4; ++ir)
#pragma unroll
            for (int jc = 0; jc < 2; ++jc) acc[ir][jc] = (f32x4){0.f, 0.f, 0.f, 0.f};

#pragma unroll
        for (int kc = 0; kc < 4; ++kc)
#pragma unroll
            for (int ir = 0; ir < 4; ++ir)
#pragma unroll
                for (int jc = 0; jc < 2; ++jc)
                    acc[ir][jc] = __builtin_amdgcn_mfma_f32_16x16x32_bf16(
                        bf_[kc][jc], af[kc][ir], acc[ir][jc], 0, 0, 0);

#pragma unroll
        for (int ir = 0; ir < 4; ++ir) {
            int row = row0 + ir * 16 + l15;
            bool live = row < N_NODES;
#pragma unroll
            for (int jc = 0; jc < 2; ++jc) {
                ushort4 o;
                o.x = f2bf(acc[ir][jc][0]); o.y = f2bf(acc[ir][jc][1]);
                o.z = f2bf(acc[ir][jc][2]); o.w = f2bf(acc[ir][jc][3]);
                *(ushort4*)&pre[(size_t)row * 128 + col0 + jc * 16 + quad * 4] = o;
                if (live) {
#pragma unroll
                    for (int r = 0; r < 4; ++r) {
                        float v = acc[ir][jc][r];
                        lsum[jc * 4 + r] += v;
                        lsq[jc * 4 + r]  += v * v;
                    }
                }
            }
        }
    }

#pragma unroll
    for (int m = 1; m < 16; m <<= 1) {
#pragma unroll
        for (int i = 0; i < 8; ++i) {
            lsum[i] += __shfl_xor(lsum[i], m);
            lsq[i]  += __shfl_xor(lsq[i], m);
        }
    }
    if (l15 == 0) {
#pragma unroll
        for (int jc = 0; jc < 2; ++jc)
#pragma unroll
            for (int r = 0; r < 4; ++r) {
                int c = col0 + jc * 16 + quad * 4 + r;
                atomicAdd(&sred[c], lsum[jc * 4 + r]);
                atomicAdd(&qred[c], lsq[jc * 4 + r]);
            }
    }
    __syncthreads();
    if (tid < 128) {
        partial[(size_t)blockIdx.x * 256 + tid]       = sred[tid];
        partial[(size_t)blockIdx.x * 256 + 128 + tid] = qred[tid];
    }
}

// ---- reduce GG partials -> scale/shift (one block per output column) ----
__global__ __launch_bounds__(256) void k_reduce(const float* __restrict__ partial,
                                                const float* __restrict__ gamma,
                                                const float* __restrict__ beta,
                                                float* __restrict__ scaleshift) {
    __shared__ float ls[256], lq[256];
    int j = blockIdx.x;   // 0..127
    int t = threadIdx.x;
    float s = 0.f, q = 0.f;
    for (int p = t; p < GG; p += 256) {
        s += partial[(size_t)p * 256 + j];
        q += partial[(size_t)p * 256 + 128 + j];
    }
    ls[t] = s; lq[t] = q;
    __syncthreads();
#pragma unroll
    for (int off = 128; off > 0; off >>= 1) {
        if (t < off) { ls[t] += ls[t + off]; lq[t] += lq[t + off]; }
        __syncthreads();
    }
    if (t == 0) {
        float mean = ls[0] * (1.0f / N_NODES);
        float var  = lq[0] * (1.0f / N_NODES) - mean * mean;
        float sc   = gamma[j] * rsqrtf(var + 1e-5f);
        scaleshift[j]       = sc;
        scaleshift[128 + j] = beta[j] - mean * sc;
    }
}

// read bf16 pre (8/thread), write fp32 out (32B/thread)
__global__ __launch_bounds__(256) void k_apply(const ushort* __restrict__ pre,
                                               float* __restrict__ out,
                                               const float* __restrict__ ss) {
    int t = blockIdx.x * blockDim.x + threadIdx.x;
    if (t >= N_NODES * 16) return;
    int j8 = t & 15;
    u16x8 p = ((const u16x8*)pre)[t];
    float4 sc0 = ((const float4*)ss)[j8 * 2];
    float4 sc1 = ((const float4*)ss)[j8 * 2 + 1];
    float4 sh0 = ((const float4*)(ss + 128))[j8 * 2];
    float4 sh1 = ((const float4*)(ss + 128))[j8 * 2 + 1];
    float4 v0, v1;
    v0.x = fmaxf(fmaf(bf2f(p[0]), sc0.x, sh0.x), 0.f);
    v0.y = fmaxf(fmaf(bf2f(p[1]), sc0.y, sh0.y), 0.f);
    v0.z = fmaxf(fmaf(bf2f(p[2]), sc0.z, sh0.z), 0.f);
    v0.w = fmaxf(fmaf(bf2f(p[3]), sc0.w, sh0.w), 0.f);
    v1.x = fmaxf(fmaf(bf2f(p[4]), sc1.x, sh1.x), 0.f);
    v1.y = fmaxf(fmaf(bf2f(p[5]), sc1.y, sh1.y), 0.f);
    v1.z = fmaxf(fmaf(bf2f(p[6]), sc1.z, sh1.z), 0.f);
    v1.w = fmaxf(fmaf(bf2f(p[7]), sc1.w, sh1.w), 0.f);
    ((float4*)out)[t * 2]     = v0;
    ((float4*)out)[t * 2 + 1] = v1;
}

extern "C" void kernel_launch(void* const* d_in, const int* in_sizes, int n_in,
                              void* d_out, int out_size, void* d_ws, size_t ws_size,
                              hipStream_t stream) {
    const float* x      = (const float*)d_in[0];
    const int*   eidx   = (const int*)d_in[1];
    const float* W      = (const float*)d_in[2];
    const float* skipW  = (const float*)d_in[4];
    const float* gamma  = (const float*)d_in[5];
    const float* beta   = (const float*)d_in[6];
    float* out = (float*)d_out;
    float* ws  = (float*)d_ws;

    const int* row = eidx;
    const int* col = eidx + E_EDGES;

    float* scaleshift = ws + OFF_SCALE;
    float* dinv       = ws + OFF_DINV;
    int*   rowptr     = (int*)(ws + OFF_ROWPTR);
    int*   deg        = (int*)(ws + OFF_DEG);
    int*   gcnt       = (int*)(ws + OFF_GCNT);
    unsigned int* binned = (unsigned int*)(ws + OFF_BINNED);
    float* partial    = ws + OFF_PART;             // aliases binned (dead after agg)
    ushort* A         = (ushort*)(ws + OFF_A);
    unsigned* xd8     = (unsigned*)(ws + OFF_XD8); // aliases pre (dead by gemm)
    ushort* pre       = (ushort*)(ws + OFF_PRE);
    ushort* Bt        = (ushort*)(ws + OFF_BT);

    k_init<<<65, 256, 0, stream>>>(W, skipW, Bt, gcnt);
    k_scatter<<<NCHUNK, 512, 0, stream>>>(row, col, gcnt, binned);
    k_sortbucket<<<NBUCK, 256, 0, stream>>>(binned, gcnt, rowptr, deg, dinv, x, xd8, A);
    k_agg<<<(N_PAD * 16 + 255) / 256, 256, 0, stream>>>(xd8, dinv, rowptr, deg, binned, A);
    k_gemm<<<GG, 512, 0, stream>>>(A, Bt, pre, partial);
    k_reduce<<<128, 256, 0, stream>>>(partial, gamma, beta, scaleshift);
    k_apply<<<(N_NODES * 16 + 255) / 256, 256, 0, stream>>>(pre, out, scaleshift);
}